// Round 15
// baseline (130.626 us; speedup 1.0000x reference)
//
#include <hip/hip_runtime.h>
#include <cstdint>
#include <cstddef>

// SpikingHybridCoreFlow: 20-cycle spiking simulation.
// Exactness strategy (unchanged): fixed-point weights (4 x i8 planes, scale
// 2^-33), i8 MFMA integer GEMM (order-independent exact), fp64 membrane.
//
// R15: R14 (104.4us) + core-0's W pack moved INTO gemm_core0 as on-the-fly
// B quantize-staging (waves 2,3: fp32 load -> reg quantize -> ds_write, one
// kstep ahead; bit-identical math to pack_unit). prep shrinks to gen-only.
// gemm_core0 is a SEPARATE kernel so its VGPR pressure cannot affect cores
// 1-3 (R8 lesson). Cores 1-3 keep the proven packed-DMA path + overlapped
// W_{c+1} pack + T5 setprio.

#define N_DIM 2048
#define B_DIM 64
#define C_DIM 4
#define T_SIM 16
#define CYCLES 20
#define M_ROWS (CYCLES * B_DIM)          // 1280

using i32x4 = __attribute__((ext_vector_type(4))) int;
using u32x4 = __attribute__((ext_vector_type(4))) uint32_t;

// Workspace layout
//   WQ  : [C][128 strips][32 ksteps][4 planes][1024B] = 67,108,864 B (W0 slot unused)
//   SIG : 4 x packed A matrices [80 mt][32 ks][1024B]  = 10,485,760 B
static constexpr size_t WQ_CORE    = (size_t)128 * 32 * 4 * 1024;   // 16 MB
static constexpr size_t SIG_OFF    = (size_t)C_DIM * WQ_CORE;
static constexpr size_t AMAT_BYTES = (size_t)M_ROWS * N_DIM;

// Packed-A byte offset for logical (m, k); m = b*20 + t.
__device__ __forceinline__ size_t apk_off(int m, int k) {
    return ((size_t)((m >> 4) * 32 + (k >> 6)) << 10)
         + (size_t)((((k >> 4) & 3) << 8) + ((m & 15) << 4) + (k & 15));
}

// Quantize one fp32 weight -> 4 balanced i8 plane bytes (scale 2^33, exact).
__device__ __forceinline__ void quant4(float wv, int& b0, int& b1, int& b2, int& b3) {
    long long vi = llrintf(wv * 8589934592.0f);            // * 2^33, exact
    int v  = (int)vi;
    b0 = (int)(signed char)(v & 255); v = (v - b0) >> 8;
    b1 = (int)(signed char)(v & 255); v = (v - b1) >> 8;
    b2 = (int)(signed char)(v & 255); v = (v - b2) >> 8;
    b3 = v;
}

// ---------------------------------------------------------------------------
// Pack one (ct,ks) block of one core's W (B-fragment order, coalesced stores).
// ---------------------------------------------------------------------------
__device__ __forceinline__ void pack_unit(const float* __restrict__ wc,
                                          signed char* __restrict__ wqc,
                                          int unit, int l) {
    int ct = unit & 127;
    int ks = unit >> 7;                // 0..31
    int n     = ct * 16 + (l & 15);
    int abase = ks * 64 + ((l >> 4) << 4);
    size_t blk_base = (((size_t)ct * 32 + ks) * 4) * 1024 + (size_t)l * 16;

    u32x4 d0, d1, d2, d3;
    for (int j4 = 0; j4 < 4; ++j4) {
        uint32_t w0 = 0, w1 = 0, w2 = 0, w3 = 0;
        for (int i = 0; i < 4; ++i) {
            int a = abase + j4 * 4 + i;
            int b0, b1, b2, b3;
            quant4(wc[(size_t)a * N_DIM + n], b0, b1, b2, b3);
            w0 |= (uint32_t)(uint8_t)b0 << (8 * i);
            w1 |= (uint32_t)(uint8_t)b1 << (8 * i);
            w2 |= (uint32_t)(uint8_t)b2 << (8 * i);
            w3 |= (uint32_t)(uint8_t)b3 << (8 * i);
        }
        d0[j4] = w0; d1[j4] = w1; d2[j4] = w2; d3[j4] = w3;
    }
    *(u32x4*)(wqc + blk_base)        = d0;
    *(u32x4*)(wqc + blk_base + 1024) = d1;
    *(u32x4*)(wqc + blk_base + 2048) = d2;
    *(u32x4*)(wqc + blk_base + 3072) = d3;
}

// ---------------------------------------------------------------------------
// Bit-exact replication of _uniform_spikes (IEEE fp32, like XLA).
// ---------------------------------------------------------------------------
__device__ __forceinline__ int in_spike(float xv, int cycle) {
    if (cycle >= T_SIM) return 0;
    float n_spk = rintf(xv * 16.0f);
    if (n_spk == 16.0f) return 1;
    if (n_spk == 0.0f)  return 0;
    float spacing = 16.0f / n_spk;
    float cf = (float)cycle;
    float q = floorf(cf / spacing);
    float r = fmodf(cf, spacing);
    return (q < n_spk && floorf(r) == 0.0f) ? 1 : 0;
}

// gen-only prep: packed core-0 A matrix, row m = b*20 + t.
__global__ __launch_bounds__(256) void gen_in(const float* __restrict__ x,
                                              signed char* __restrict__ a0) {
    int gid = blockIdx.x * 256 + threadIdx.x;      // 0 .. 655359
    int e   = gid << 2;
    int row = e >> 11;
    int b = row / 20, t = row - b * 20;
    int n0 = e & 2047;
    const float4 xv = *(const float4*)(x + (size_t)b * N_DIM + n0);
    uint32_t s = (uint32_t)in_spike(xv.x, t)
               | ((uint32_t)in_spike(xv.y, t) << 8)
               | ((uint32_t)in_spike(xv.z, t) << 16)
               | ((uint32_t)in_spike(xv.w, t) << 24);
    *(uint32_t*)(a0 + apk_off(row, n0)) = s;
}

// ---------------------------------------------------------------------------
// Shared epilogue: exact plane combine -> fp64 scr -> per-(b,n) scan.
// ---------------------------------------------------------------------------
__device__ __forceinline__ void epilogue(
        signed char* smem, i32x4 (*acc)[4], int tid, int l, int nc, int mtb,
        int e8, int s, const float* biases, const float* thresholds,
        signed char* a_next, float* out, int c)
{
    double* scr = (double*)smem;       // [160][33]
    const int nl = nc * 16 + (l & 15);
#pragma unroll
    for (int j = 0; j < 5; ++j) {
#pragma unroll
        for (int r = 0; r < 4; ++r) {
            int rl = (mtb + j) * 16 + ((l >> 4) << 2) + r;
            long long comb = ((long long)acc[j][3][r] << 24) + ((long long)acc[j][2][r] << 16)
                           + ((long long)acc[j][1][r] << 8)  +  (long long)acc[j][0][r];
            scr[rl * 33 + nl] = (double)comb * (1.0 / 8589934592.0);
        }
    }
    __syncthreads();

    const int b_loc = tid >> 5;
    const int n_loc = tid & 31;
    const int b = e8 * 8 + b_loc;
    const int n = (s << 5) + n_loc;
    const double bv = (double)biases[c * N_DIM + n];
    const double th = (double)thresholds[c];
    double m = 0.0;
    float cnt = 0.0f;
    if (c < 3) a_next[apk_off(b * 20, n)] = 0;
    for (int t = 0; t < CYCLES; ++t) {
        m = m + scr[(b_loc * 20 + t) * 33 + n_loc] + bv;
        bool sp = (th < m);
        if (sp) m -= th;
        if (c < 3) {
            if (t + 1 < CYCLES) a_next[apk_off(b * 20 + t + 1, n)] = sp ? 1 : 0;
        } else if (sp) {
            cnt += 1.0f;
        }
    }
    if (c == 3) out[(size_t)b * N_DIM + n] = cnt * 0.0625f;
}

// ---------------------------------------------------------------------------
// Cores 1-3: R14 kernel (packed-B DMA staging + overlapped W_{c+1} pack).
// ---------------------------------------------------------------------------
__global__ __launch_bounds__(256, 2) void gemm_core(
        signed char* __restrict__ wq, const signed char* __restrict__ apk,
        const float* __restrict__ wts, const float* __restrict__ biases,
        const float* __restrict__ thresholds,
        signed char* __restrict__ a_next, float* __restrict__ out, int c)
{
    __shared__ __align__(16) signed char smem[42240];
    const int wg  = blockIdx.x;
    const int tid = threadIdx.x;
    const int wv  = tid >> 6;
    const int l   = tid & 63;

    if (wg >= 512) {                   // overlapped pack of W_{c+1}
        pack_unit(wts + (size_t)(c + 1) * N_DIM * N_DIM,
                  wq + (size_t)(c + 1) * WQ_CORE,
                  ((wg - 512) << 2) | wv, l);
        return;
    }

    const int e8 = wg >> 6;
    const int s  = wg & 63;

    const signed char* asrc  = apk + ((size_t)(e8 * 10) * 32) * 1024;
    const signed char* b0src = wq + ((size_t)(c * 128 + s * 2) * 32) * 4096;
    const signed char* b1src = wq + ((size_t)(c * 128 + s * 2 + 1) * 32) * 4096;

    auto STAGE = [&](int buf, int ks) {
        signed char* dst = smem + buf * 18432;
        if (wv < 2) {
#pragma unroll
            for (int r = 0; r < 5; ++r) {
                int blk = wv * 5 + r;
                __builtin_amdgcn_global_load_lds(
                    (const __attribute__((address_space(1))) uint32_t*)
                        (asrc + ((size_t)blk * 32 + ks) * 1024 + l * 16),
                    (__attribute__((address_space(3))) uint32_t*)(dst + blk * 1024),
                    16, 0, 0);
            }
        } else {
            const signed char* bs = (wv == 2) ? b0src : b1src;
#pragma unroll
            for (int p = 0; p < 4; ++p) {
                __builtin_amdgcn_global_load_lds(
                    (const __attribute__((address_space(1))) uint32_t*)
                        (bs + (size_t)ks * 4096 + p * 1024 + l * 16),
                    (__attribute__((address_space(3))) uint32_t*)
                        (dst + 10240 + (wv - 2) * 4096 + p * 1024),
                    16, 0, 0);
            }
        }
    };

    const int nc  = wv & 1;
    const int mtb = (wv >> 1) * 5;

    i32x4 acc[5][4];
#pragma unroll
    for (int j = 0; j < 5; ++j)
#pragma unroll
        for (int p = 0; p < 4; ++p) acc[j][p] = i32x4{0, 0, 0, 0};

    STAGE(0, 0);
    __syncthreads();
    int cur = 0;

    for (int ks = 0; ks < 32; ++ks) {
        if (ks < 31) STAGE(cur ^ 1, ks + 1);
        const signed char* lb = smem + cur * 18432 + (size_t)l * 16;
        i32x4 bf0 = *(const i32x4*)(lb + 10240 + nc * 4096);
        i32x4 bf1 = *(const i32x4*)(lb + 10240 + nc * 4096 + 1024);
        i32x4 bf2 = *(const i32x4*)(lb + 10240 + nc * 4096 + 2048);
        i32x4 bf3 = *(const i32x4*)(lb + 10240 + nc * 4096 + 3072);
        __builtin_amdgcn_s_setprio(1);
#pragma unroll
        for (int j = 0; j < 5; ++j) {
            i32x4 af = *(const i32x4*)(lb + (mtb + j) * 1024);
            acc[j][0] = __builtin_amdgcn_mfma_i32_16x16x64_i8(af, bf0, acc[j][0], 0, 0, 0);
            acc[j][1] = __builtin_amdgcn_mfma_i32_16x16x64_i8(af, bf1, acc[j][1], 0, 0, 0);
            acc[j][2] = __builtin_amdgcn_mfma_i32_16x16x64_i8(af, bf2, acc[j][2], 0, 0, 0);
            acc[j][3] = __builtin_amdgcn_mfma_i32_16x16x64_i8(af, bf3, acc[j][3], 0, 0, 0);
        }
        __builtin_amdgcn_s_setprio(0);
        __syncthreads();
        cur ^= 1;
    }

    epilogue(smem, acc, tid, l, nc, mtb, e8, s, biases, thresholds, a_next, out, c);
}

// ---------------------------------------------------------------------------
// Core 0: B staged by on-the-fly quantization of fp32 W0 (waves 2,3), one
// kstep ahead (fp32 loads double-buffered in registers). Also packs W1 via
// wg>=512 blocks. Separate kernel so its VGPRs don't affect cores 1-3.
// ---------------------------------------------------------------------------
__global__ __launch_bounds__(256, 2) void gemm_core0(
        signed char* __restrict__ wq, const signed char* __restrict__ apk,
        const float* __restrict__ wts, const float* __restrict__ biases,
        const float* __restrict__ thresholds,
        signed char* __restrict__ a_next, float* __restrict__ out)
{
    __shared__ __align__(16) signed char smem[42240];
    const int wg  = blockIdx.x;
    const int tid = threadIdx.x;
    const int wv  = tid >> 6;
    const int l   = tid & 63;

    if (wg >= 512) {                   // overlapped pack of W1
        pack_unit(wts + (size_t)1 * N_DIM * N_DIM,
                  wq + (size_t)1 * WQ_CORE,
                  ((wg - 512) << 2) | wv, l);
        return;
    }

    const int e8 = wg >> 6;
    const int s  = wg & 63;
    const int nc  = wv & 1;
    const int mtb = (wv >> 1) * 5;

    const signed char* asrc = apk + ((size_t)(e8 * 10) * 32) * 1024;
    // fp32 W0 source for waves 2,3: strip s2, element (k, n):
    //   n = s2*16 + (l&15), k = ks*64 + (l>>4)*16 + j
    const int s2 = s * 2 + (wv - 2);   // valid only for wv >= 2
    const float* bsrc32 = wts + (size_t)(((l >> 4) << 4)) * N_DIM
                        + (wv >= 2 ? (s2 * 16 + (l & 15)) : 0);

    auto STAGE_A = [&](int buf, int ks) {
        signed char* dst = smem + buf * 18432;
#pragma unroll
        for (int r = 0; r < 5; ++r) {
            int blk = wv * 5 + r;
            __builtin_amdgcn_global_load_lds(
                (const __attribute__((address_space(1))) uint32_t*)
                    (asrc + ((size_t)blk * 32 + ks) * 1024 + l * 16),
                (__attribute__((address_space(3))) uint32_t*)(dst + blk * 1024),
                16, 0, 0);
        }
    };
    auto LOADF = [&](float* f, int ks) {
        const float* p = bsrc32 + (size_t)ks * 64 * N_DIM;
#pragma unroll
        for (int j = 0; j < 16; ++j) f[j] = p[(size_t)j * N_DIM];
    };
    auto QSTORE = [&](int buf, const float* f) {
        signed char* dst = smem + buf * 18432 + 10240 + (wv - 2) * 4096 + l * 16;
        u32x4 q0{0,0,0,0}, q1{0,0,0,0}, q2{0,0,0,0}, q3{0,0,0,0};
#pragma unroll
        for (int j = 0; j < 16; ++j) {
            int b0, b1, b2, b3;
            quant4(f[j], b0, b1, b2, b3);
            const int d = j >> 2, sh = 8 * (j & 3);
            q0[d] |= (uint32_t)(uint8_t)b0 << sh;
            q1[d] |= (uint32_t)(uint8_t)b1 << sh;
            q2[d] |= (uint32_t)(uint8_t)b2 << sh;
            q3[d] |= (uint32_t)(uint8_t)b3 << sh;
        }
        *(u32x4*)(dst)        = q0;
        *(u32x4*)(dst + 1024) = q1;
        *(u32x4*)(dst + 2048) = q2;
        *(u32x4*)(dst + 3072) = q3;
    };

    i32x4 acc[5][4];
#pragma unroll
    for (int j = 0; j < 5; ++j)
#pragma unroll
        for (int p = 0; p < 4; ++p) acc[j][p] = i32x4{0, 0, 0, 0};

    float fA[16], fB[16];
    // Prologue: stage slice 0 (A via DMA; B via quantize), preload f(1).
    if (wv < 2) {
        STAGE_A(0, 0);
    } else {
        LOADF(fA, 0);
        QSTORE(0, fA);
        LOADF(fA, 1);                  // fA now holds slice 1
    }
    __syncthreads();
    int cur = 0;

#pragma unroll 1
    for (int k2 = 0; k2 < 16; ++k2) {
        const int ks = k2 * 2;
        // even: stage slice ks+1 into buf^1; compute slice ks.
        if (wv < 2) {
            STAGE_A(cur ^ 1, ks + 1);
        } else {
            QSTORE(cur ^ 1, fA);                       // B(ks+1)
            LOADF(fB, ks + 2 < 32 ? ks + 2 : 31);      // f(ks+2)
        }
        {
            const signed char* lb = smem + cur * 18432 + (size_t)l * 16;
            i32x4 bf0 = *(const i32x4*)(lb + 10240 + nc * 4096);
            i32x4 bf1 = *(const i32x4*)(lb + 10240 + nc * 4096 + 1024);
            i32x4 bf2 = *(const i32x4*)(lb + 10240 + nc * 4096 + 2048);
            i32x4 bf3 = *(const i32x4*)(lb + 10240 + nc * 4096 + 3072);
            __builtin_amdgcn_s_setprio(1);
#pragma unroll
            for (int j = 0; j < 5; ++j) {
                i32x4 af = *(const i32x4*)(lb + (mtb + j) * 1024);
                acc[j][0] = __builtin_amdgcn_mfma_i32_16x16x64_i8(af, bf0, acc[j][0], 0, 0, 0);
                acc[j][1] = __builtin_amdgcn_mfma_i32_16x16x64_i8(af, bf1, acc[j][1], 0, 0, 0);
                acc[j][2] = __builtin_amdgcn_mfma_i32_16x16x64_i8(af, bf2, acc[j][2], 0, 0, 0);
                acc[j][3] = __builtin_amdgcn_mfma_i32_16x16x64_i8(af, bf3, acc[j][3], 0, 0, 0);
            }
            __builtin_amdgcn_s_setprio(0);
        }
        __syncthreads();
        cur ^= 1;
        // odd: stage slice ks+2 (if any); compute slice ks+1.
        if (wv < 2) {
            if (ks + 2 < 32) STAGE_A(cur ^ 1, ks + 2);
        } else if (ks + 2 < 32) {
            QSTORE(cur ^ 1, fB);                       // B(ks+2)
            LOADF(fA, ks + 3 < 32 ? ks + 3 : 31);      // f(ks+3)
        }
        {
            const signed char* lb = smem + cur * 18432 + (size_t)l * 16;
            i32x4 bf0 = *(const i32x4*)(lb + 10240 + nc * 4096);
            i32x4 bf1 = *(const i32x4*)(lb + 10240 + nc * 4096 + 1024);
            i32x4 bf2 = *(const i32x4*)(lb + 10240 + nc * 4096 + 2048);
            i32x4 bf3 = *(const i32x4*)(lb + 10240 + nc * 4096 + 3072);
            __builtin_amdgcn_s_setprio(1);
#pragma unroll
            for (int j = 0; j < 5; ++j) {
                i32x4 af = *(const i32x4*)(lb + (mtb + j) * 1024);
                acc[j][0] = __builtin_amdgcn_mfma_i32_16x16x64_i8(af, bf0, acc[j][0], 0, 0, 0);
                acc[j][1] = __builtin_amdgcn_mfma_i32_16x16x64_i8(af, bf1, acc[j][1], 0, 0, 0);
                acc[j][2] = __builtin_amdgcn_mfma_i32_16x16x64_i8(af, bf2, acc[j][2], 0, 0, 0);
                acc[j][3] = __builtin_amdgcn_mfma_i32_16x16x64_i8(af, bf3, acc[j][3], 0, 0, 0);
            }
            __builtin_amdgcn_s_setprio(0);
        }
        __syncthreads();
        cur ^= 1;
    }

    epilogue(smem, acc, tid, l, nc, mtb, e8, s, biases, thresholds, a_next, out, 0);
}

extern "C" void kernel_launch(void* const* d_in, const int* in_sizes, int n_in,
                              void* d_out, int out_size, void* d_ws, size_t ws_size,
                              hipStream_t stream) {
    const float* x       = (const float*)d_in[0];
    const float* wts     = (const float*)d_in[1];
    const float* biases  = (const float*)d_in[2];
    const float* thr     = (const float*)d_in[3];
    float* out           = (float*)d_out;

    signed char* wq  = (signed char*)d_ws;
    signed char* sig = (signed char*)((char*)d_ws + SIG_OFF);

    // prep: input spike gen only (core-0 W is quantized on the fly).
    gen_in<<<dim3(2560), dim3(256), 0, stream>>>(x, sig);

    // Core 0: fp32-quantize-staged B + overlapped W1 pack.
    gemm_core0<<<dim3(1536), dim3(256), 0, stream>>>(
        wq, sig, wts, biases, thr, sig + AMAT_BYTES, out);

    // Cores 1-3: packed-B DMA path (+ overlapped W_{c+1} pack for c<3).
    for (int c = 1; c < C_DIM; ++c) {
        const signed char* a_cur = sig + (size_t)c * AMAT_BYTES;
        signed char* a_nxt = (c < 3) ? (signed char*)(sig + (size_t)(c + 1) * AMAT_BYTES)
                                     : (signed char*)sig;   // unused for c==3
        int grid = (c < 3) ? 1536 : 512;
        gemm_core<<<dim3(grid), dim3(256), 0, stream>>>(wq, a_cur, wts, biases,
                                                        thr, a_nxt, out, c);
    }
}

// Round 16
// 104.051 us; speedup vs baseline: 1.2554x; 1.2554x over previous
//
#include <hip/hip_runtime.h>
#include <cstdint>
#include <cstddef>

// SpikingHybridCoreFlow: 20-cycle spiking simulation.
// Exactness strategy (unchanged): fixed-point weights (4 x i8 planes, scale
// 2^-33), i8 MFMA integer GEMM (order-independent exact), fp64 membrane.
//
// R16: exact revert to R14 (best measured: 104.4us). R15's on-the-fly
// quantize regressed (gemm_core0 60us: strided fp32 loads + quantize VALU
// sat INSIDE the per-kstep stage critical path). Final structure:
//   prep0: pack W0 (coalesced dwordx4) + gen packed A0, one launch
//   4x gemm_core: 2-phase LDS-staged i8 MFMA GEMM (128x32-col tiles,
//     5/5/4/4 DMA stage split, 42,240B block -> 3 WGs/CU, T5 setprio on
//     the MFMA cluster) + fused exact fp64 threshold-scan epilogue
//     + W_{c+1} pack overlapped as extra blocks (c<3).

#define N_DIM 2048
#define B_DIM 64
#define C_DIM 4
#define T_SIM 16
#define CYCLES 20
#define M_ROWS (CYCLES * B_DIM)          // 1280

using i32x4 = __attribute__((ext_vector_type(4))) int;
using u32x4 = __attribute__((ext_vector_type(4))) uint32_t;

// Workspace layout
//   WQ  : [C][128 strips][32 ksteps][4 planes][1024B] = 67,108,864 B
//   SIG : 4 x packed A matrices [80 mt][32 ks][1024B]  = 10,485,760 B
static constexpr size_t WQ_CORE    = (size_t)128 * 32 * 4 * 1024;   // 16 MB
static constexpr size_t SIG_OFF    = (size_t)C_DIM * WQ_CORE;
static constexpr size_t AMAT_BYTES = (size_t)M_ROWS * N_DIM;

// Packed-A byte offset for logical (m, k); m = b*20 + t.
//   block = (m>>4)*32 + (k>>6); in-block = ((k>>4)&3)*256 + (m&15)*16 + (k&15)
// = the i8 16x16x64 A-fragment order (lane*16 + j).
__device__ __forceinline__ size_t apk_off(int m, int k) {
    return ((size_t)((m >> 4) * 32 + (k >> 6)) << 10)
         + (size_t)((((k >> 4) & 3) << 8) + ((m & 15) << 4) + (k & 15));
}

// ---------------------------------------------------------------------------
// Pack one (ct,ks) block of one core's W: fp32 -> i32 fixed point (scale 2^33)
// -> 4 balanced i8 planes, MFMA B-fragment order, coalesced dwordx4 stores.
// ---------------------------------------------------------------------------
__device__ __forceinline__ void pack_unit(const float* __restrict__ wc,
                                          signed char* __restrict__ wqc,
                                          int unit, int l) {
    int ct = unit & 127;
    int ks = unit >> 7;                // 0..31
    int n     = ct * 16 + (l & 15);
    int abase = ks * 64 + ((l >> 4) << 4);
    size_t blk_base = (((size_t)ct * 32 + ks) * 4) * 1024 + (size_t)l * 16;

    u32x4 d0, d1, d2, d3;
    for (int j4 = 0; j4 < 4; ++j4) {
        uint32_t w0 = 0, w1 = 0, w2 = 0, w3 = 0;
        for (int i = 0; i < 4; ++i) {
            int a = abase + j4 * 4 + i;
            float wv = wc[(size_t)a * N_DIM + n];
            long long vi = llrintf(wv * 8589934592.0f);        // * 2^33, exact
            int v  = (int)vi;
            int b0 = (int)(signed char)(v & 255); v = (v - b0) >> 8;
            int b1 = (int)(signed char)(v & 255); v = (v - b1) >> 8;
            int b2 = (int)(signed char)(v & 255); v = (v - b2) >> 8;
            int b3 = v;
            w0 |= (uint32_t)(uint8_t)b0 << (8 * i);
            w1 |= (uint32_t)(uint8_t)b1 << (8 * i);
            w2 |= (uint32_t)(uint8_t)b2 << (8 * i);
            w3 |= (uint32_t)(uint8_t)b3 << (8 * i);
        }
        d0[j4] = w0; d1[j4] = w1; d2[j4] = w2; d3[j4] = w3;
    }
    *(u32x4*)(wqc + blk_base)        = d0;
    *(u32x4*)(wqc + blk_base + 1024) = d1;
    *(u32x4*)(wqc + blk_base + 2048) = d2;
    *(u32x4*)(wqc + blk_base + 3072) = d3;
}

// ---------------------------------------------------------------------------
// Bit-exact replication of _uniform_spikes (IEEE fp32, like XLA).
// ---------------------------------------------------------------------------
__device__ __forceinline__ int in_spike(float xv, int cycle) {
    if (cycle >= T_SIM) return 0;
    float n_spk = rintf(xv * 16.0f);
    if (n_spk == 16.0f) return 1;
    if (n_spk == 0.0f)  return 0;
    float spacing = 16.0f / n_spk;
    float cf = (float)cycle;
    float q = floorf(cf / spacing);
    float r = fmodf(cf, spacing);
    return (q < n_spk && floorf(r) == 0.0f) ? 1 : 0;
}

// Packed core-0 A element group: row m = b*20 + t, 4 n's per thread.
__device__ __forceinline__ void gen_unit(const float* __restrict__ x,
                                         signed char* __restrict__ a0, int gid) {
    int e   = gid << 2;                            // logical m*2048 + n byte idx
    int row = e >> 11;                             // m = b*20 + t
    int b = row / 20, t = row - b * 20;
    int n0 = e & 2047;
    const float4 xv = *(const float4*)(x + (size_t)b * N_DIM + n0);
    uint32_t s = (uint32_t)in_spike(xv.x, t)
               | ((uint32_t)in_spike(xv.y, t) << 8)
               | ((uint32_t)in_spike(xv.z, t) << 16)
               | ((uint32_t)in_spike(xv.w, t) << 24);
    *(uint32_t*)(a0 + apk_off(row, n0)) = s;
}

// prep0: blocks [0,1024) pack core-0 W (4 units each); [1024,3584) gen input.
__global__ __launch_bounds__(256) void prep0(const float* __restrict__ w,
                                             signed char* __restrict__ wq,
                                             const float* __restrict__ x,
                                             signed char* __restrict__ a0) {
    int wg = blockIdx.x, tid = threadIdx.x;
    if (wg < 1024) {
        pack_unit(w, wq, (wg << 2) | (tid >> 6), tid & 63);
    } else {
        gen_unit(x, a0, (wg - 1024) * 256 + tid);
    }
}

// ---------------------------------------------------------------------------
// Fused batched-GEMM + threshold-scan for one core, + overlapped W_{c+1} pack.
// Gemm WGs (wg<512): 8 m-eighths (8 b's = 160 rows = 10 m-tiles) x 64 strips
// (32 cols). 256 thr = 4 waves; wave wv: nc = wv&1, m-tiles (wv>>1)*5+0..4
// -> acc[5][4] (80 VGPR). Per kstep stage 18KB (10 A + 8 B blocks) into
// lds[buf^1] before computing lds[buf] (20 MFMAs/wave, setprio-wrapped);
// one __syncthreads per kstep. 42,240B block -> up to 3 WGs/CU.
// Epilogue: exact plane combine -> fp64 scr[160][33] -> per-(b,n) 20-step
// threshold scan -> packed spikes for next core / output.
// Pack WGs (wg>=512, c<3): pack W_{c+1} (memory-bound, overlaps gemm).
// ---------------------------------------------------------------------------
__global__ __launch_bounds__(256, 2) void gemm_core(
        signed char* __restrict__ wq, const signed char* __restrict__ apk,
        const float* __restrict__ wts, const float* __restrict__ biases,
        const float* __restrict__ thresholds,
        signed char* __restrict__ a_next, float* __restrict__ out, int c)
{
    __shared__ __align__(16) signed char smem[42240];   // 2x18KB stage / scr
    const int wg  = blockIdx.x;
    const int tid = threadIdx.x;
    const int wv  = tid >> 6;          // 0..3
    const int l   = tid & 63;

    if (wg >= 512) {                   // overlapped pack of W_{c+1}
        pack_unit(wts + (size_t)(c + 1) * N_DIM * N_DIM,
                  wq + (size_t)(c + 1) * WQ_CORE,
                  ((wg - 512) << 2) | wv, l);
        return;
    }

    const int e8 = wg >> 6;            // m-eighth: b in [8*e8, 8*e8+8)
    const int s  = wg & 63;            // 32-col strip: n in [32s, 32s+32)

    const signed char* asrc  = apk + ((size_t)(e8 * 10) * 32) * 1024;
    const signed char* b0src = wq + ((size_t)(c * 128 + s * 2) * 32) * 4096;
    const signed char* b1src = wq + ((size_t)(c * 128 + s * 2 + 1) * 32) * 4096;

    // Stage slice ks into buffer buf. Waves 0,1: A blocks (5 each);
    // waves 2,3: B strip0/strip1 (4 plane-blocks each). 1KB per DMA load.
    auto STAGE = [&](int buf, int ks) {
        signed char* dst = smem + buf * 18432;
        if (wv < 2) {
#pragma unroll
            for (int r = 0; r < 5; ++r) {
                int blk = wv * 5 + r;
                __builtin_amdgcn_global_load_lds(
                    (const __attribute__((address_space(1))) uint32_t*)
                        (asrc + ((size_t)blk * 32 + ks) * 1024 + l * 16),
                    (__attribute__((address_space(3))) uint32_t*)(dst + blk * 1024),
                    16, 0, 0);
            }
        } else {
            const signed char* bs = (wv == 2) ? b0src : b1src;
#pragma unroll
            for (int p = 0; p < 4; ++p) {
                __builtin_amdgcn_global_load_lds(
                    (const __attribute__((address_space(1))) uint32_t*)
                        (bs + (size_t)ks * 4096 + p * 1024 + l * 16),
                    (__attribute__((address_space(3))) uint32_t*)
                        (dst + 10240 + (wv - 2) * 4096 + p * 1024),
                    16, 0, 0);
            }
        }
    };

    const int nc  = wv & 1;            // n-fragment (16 cols)
    const int mtb = (wv >> 1) * 5;     // first of 5 m-tiles

    i32x4 acc[5][4];
#pragma unroll
    for (int j = 0; j < 5; ++j)
#pragma unroll
        for (int p = 0; p < 4; ++p) acc[j][p] = i32x4{0, 0, 0, 0};

    STAGE(0, 0);
    __syncthreads();
    int cur = 0;

    for (int ks = 0; ks < 32; ++ks) {
        if (ks < 31) STAGE(cur ^ 1, ks + 1);
        const signed char* lb = smem + cur * 18432 + (size_t)l * 16;
        i32x4 bf0 = *(const i32x4*)(lb + 10240 + nc * 4096);
        i32x4 bf1 = *(const i32x4*)(lb + 10240 + nc * 4096 + 1024);
        i32x4 bf2 = *(const i32x4*)(lb + 10240 + nc * 4096 + 2048);
        i32x4 bf3 = *(const i32x4*)(lb + 10240 + nc * 4096 + 3072);
        __builtin_amdgcn_s_setprio(1);             // T5: favor MFMA cluster
#pragma unroll
        for (int j = 0; j < 5; ++j) {
            i32x4 af = *(const i32x4*)(lb + (mtb + j) * 1024);
            acc[j][0] = __builtin_amdgcn_mfma_i32_16x16x64_i8(af, bf0, acc[j][0], 0, 0, 0);
            acc[j][1] = __builtin_amdgcn_mfma_i32_16x16x64_i8(af, bf1, acc[j][1], 0, 0, 0);
            acc[j][2] = __builtin_amdgcn_mfma_i32_16x16x64_i8(af, bf2, acc[j][2], 0, 0, 0);
            acc[j][3] = __builtin_amdgcn_mfma_i32_16x16x64_i8(af, bf3, acc[j][3], 0, 0, 0);
        }
        __builtin_amdgcn_s_setprio(0);
        __syncthreads();
        cur ^= 1;
    }

    // ---- Fused epilogue ----
    // 1. Combine planes exactly -> fp64 increments into LDS (staging is dead).
    double* scr = (double*)smem;       // [160][33]
    const int nl = nc * 16 + (l & 15);
#pragma unroll
    for (int j = 0; j < 5; ++j) {
#pragma unroll
        for (int r = 0; r < 4; ++r) {
            int rl = (mtb + j) * 16 + ((l >> 4) << 2) + r;   // local row 0..159
            long long comb = ((long long)acc[j][3][r] << 24) + ((long long)acc[j][2][r] << 16)
                           + ((long long)acc[j][1][r] << 8)  +  (long long)acc[j][0][r];
            scr[rl * 33 + nl] = (double)comb * (1.0 / 8589934592.0);
        }
    }
    __syncthreads();

    // 2. Per-(b,n) threshold scan over t=0..19; thread <-> (b_loc, n_loc).
    const int b_loc = tid >> 5;        // 0..7
    const int n_loc = tid & 31;        // 0..31
    const int b = e8 * 8 + b_loc;
    const int n = (s << 5) + n_loc;
    const double bv = (double)biases[c * N_DIM + n];
    const double th = (double)thresholds[c];
    double m = 0.0;
    float cnt = 0.0f;
    if (c < 3) a_next[apk_off(b * 20, n)] = 0;     // zero input at t=0
    for (int t = 0; t < CYCLES; ++t) {
        m = m + scr[(b_loc * 20 + t) * 33 + n_loc] + bv;
        bool sp = (th < m);
        if (sp) m -= th;
        if (c < 3) {
            if (t + 1 < CYCLES) a_next[apk_off(b * 20 + t + 1, n)] = sp ? 1 : 0;
        } else if (sp) {
            cnt += 1.0f;
        }
    }
    if (c == 3) out[(size_t)b * N_DIM + n] = cnt * 0.0625f;  // /16, exact
}

extern "C" void kernel_launch(void* const* d_in, const int* in_sizes, int n_in,
                              void* d_out, int out_size, void* d_ws, size_t ws_size,
                              hipStream_t stream) {
    const float* x       = (const float*)d_in[0];
    const float* wts     = (const float*)d_in[1];
    const float* biases  = (const float*)d_in[2];
    const float* thr     = (const float*)d_in[3];
    float* out           = (float*)d_out;

    signed char* wq  = (signed char*)d_ws;
    signed char* sig = (signed char*)((char*)d_ws + SIG_OFF);

    // prep0: pack W0 + build packed core-0 input spikes (no memsets needed:
    // every consumed byte is written by a producer before its consumer runs).
    prep0<<<dim3(3584), dim3(256), 0, stream>>>(wts, wq, x, sig);

    // 4 pipeline stages: fused GEMM+scan, with W_{c+1} pack overlapped.
    for (int c = 0; c < C_DIM; ++c) {
        const signed char* a_cur = sig + (size_t)c * AMAT_BYTES;
        signed char* a_nxt = (c < 3) ? (signed char*)(sig + (size_t)(c + 1) * AMAT_BYTES)
                                     : (signed char*)sig;   // unused for c==3
        int grid = (c < 3) ? 1536 : 512;
        gemm_core<<<dim3(grid), dim3(256), 0, stream>>>(wq, a_cur, wts, biases,
                                                        thr, a_nxt, out, c);
    }
}